// Round 1
// baseline (1192.410 us; speedup 1.0000x reference)
//
#include <hip/hip_runtime.h>

typedef short s16x8 __attribute__((ext_vector_type(8)));
typedef float f32x4 __attribute__((ext_vector_type(4)));
typedef unsigned short u16;
typedef u16 u16x4 __attribute__((ext_vector_type(4)));

#define NBATCH 16
#define NSEQ   2048
#define NHID   1024
#define NATT   1024
#define MALL   (NBATCH * NSEQ)   // 32768

__device__ __forceinline__ float bf16_hi_f(float x) {
    return __uint_as_float(__float_as_uint(x) & 0xffff0000u);
}
__device__ __forceinline__ u16 bf16_trunc(float x) {
    return (u16)(__float_as_uint(x) >> 16);
}
__device__ __forceinline__ u16 bf16_rne(float x) {
    unsigned u = __float_as_uint(x);
    unsigned r = u + 0x7fffu + ((u >> 16) & 1u);
    return (u16)(r >> 16);
}
__device__ __forceinline__ float fast_tanh(float x) {
    // 1 - 2/(exp(2x)+1); exact at +-inf saturation, ~1e-6 rel err
    float e = __expf(2.0f * x);
    return 1.0f - 2.0f / (e + 1.0f);
}

// ---------------------------------------------------------------------------
// P1: transpose + split w_a and query:  wT_*[n][h] = split(w[h][n])
// ---------------------------------------------------------------------------
__global__ __launch_bounds__(256) void wsplit_kernel(
    const float* __restrict__ wa, const float* __restrict__ qu,
    u16* __restrict__ waT_hi, u16* __restrict__ waT_lo,
    u16* __restrict__ quT_hi, u16* __restrict__ quT_lo)
{
    int idx = blockIdx.x * 256 + threadIdx.x;   // 0 .. 1M-1
    int h = idx >> 10, n = idx & 1023;
    float va = wa[idx];
    float vq = qu[idx];
    int o = n * 1024 + h;
    float ha = bf16_hi_f(va);
    waT_hi[o] = bf16_trunc(va);
    waT_lo[o] = bf16_rne(va - ha);
    float hq = bf16_hi_f(vq);
    quT_hi[o] = bf16_trunc(vq);
    quT_lo[o] = bf16_rne(vq - hq);
}

// ---------------------------------------------------------------------------
// P2: xT[b][h][t] = bf16(x[b][t][h])   (LDS tile transpose, 64x64)
// ---------------------------------------------------------------------------
__global__ __launch_bounds__(256) void xT_kernel(
    const float* __restrict__ x, u16* __restrict__ xT)
{
    __shared__ u16 tile[64][65];
    int b = blockIdx.z;
    int t0 = blockIdx.x * 64;
    int h0 = blockIdx.y * 64;
    const float* xb = x + (size_t)b * NSEQ * NHID;
    u16* xTb = xT + (size_t)b * NHID * NSEQ;
    int tid = threadIdx.x;
    #pragma unroll
    for (int i = 0; i < 16; i++) {
        int e = i * 256 + tid;
        int tl = e >> 6, hl = e & 63;
        tile[tl][hl] = bf16_rne(xb[(size_t)(t0 + tl) * NHID + h0 + hl]);
    }
    __syncthreads();
    #pragma unroll
    for (int i = 0; i < 16; i++) {
        int e = i * 256 + tid;
        int hl = e >> 6, tl = e & 63;
        xTb[(size_t)(h0 + hl) * NSEQ + t0 + tl] = tile[tl][hl];
    }
}

// ---------------------------------------------------------------------------
// K1: key = tanh(x @ w_a), q = x @ query — split-bf16 MFMA GEMM
//     M=32768, N=2048 (0..1023 -> key via w_a, 1024..2047 -> q via query), K=1024
//     Outputs written pre-split (hi/lo bf16) for K2.
// ---------------------------------------------------------------------------
__global__ __launch_bounds__(256) void k1_gemm(
    const float* __restrict__ x,
    const u16* __restrict__ waT_hi, const u16* __restrict__ waT_lo,
    const u16* __restrict__ quT_hi, const u16* __restrict__ quT_lo,
    u16* __restrict__ k_hi, u16* __restrict__ k_lo,
    u16* __restrict__ q_hi, u16* __restrict__ q_lo)
{
    const int LDA = 40;
    __shared__ u16 sa_hi[128 * 40], sa_lo[128 * 40];
    __shared__ u16 sb_hi[128 * 40], sb_lo[128 * 40];

    int n0 = blockIdx.x * 128;      // 0..2047
    int m0 = blockIdx.y * 128;      // 0..32767
    bool is_key = (n0 < 1024);
    const u16* bT_hi = is_key ? waT_hi : quT_hi;
    const u16* bT_lo = is_key ? waT_lo : quT_lo;
    int bn0 = is_key ? n0 : (n0 - 1024);

    int tid = threadIdx.x;
    int lane = tid & 63;
    int wid = tid >> 6;
    int wr = wid >> 1, wc = wid & 1;

    f32x4 acc[4][4] = {};

    for (int kk = 0; kk < 1024; kk += 32) {
        __syncthreads();
        // stage A: x[m0..+128][kk..+32] f32 -> trunc-split hi/lo
        #pragma unroll
        for (int i = 0; i < 4; i++) {
            int e = i * 256 + tid;          // float4 index, 1024 total
            int row = e >> 3, c4 = e & 7;
            float4 v = *(const float4*)&x[(size_t)(m0 + row) * 1024 + kk + c4 * 4];
            float f0 = v.x, f1 = v.y, f2 = v.z, f3 = v.w;
            u16x4 hi, lo;
            hi[0] = bf16_trunc(f0); lo[0] = bf16_rne(f0 - bf16_hi_f(f0));
            hi[1] = bf16_trunc(f1); lo[1] = bf16_rne(f1 - bf16_hi_f(f1));
            hi[2] = bf16_trunc(f2); lo[2] = bf16_rne(f2 - bf16_hi_f(f2));
            hi[3] = bf16_trunc(f3); lo[3] = bf16_rne(f3 - bf16_hi_f(f3));
            *(u16x4*)&sa_hi[row * LDA + c4 * 4] = hi;
            *(u16x4*)&sa_lo[row * LDA + c4 * 4] = lo;
        }
        // stage B: wT[bn0..+128][kk..+32] pre-split bf16
        #pragma unroll
        for (int i = 0; i < 2; i++) {
            int e = i * 256 + tid;          // short8 index, 512 total
            int row = e >> 2, c8 = e & 3;
            size_t g = (size_t)(bn0 + row) * 1024 + kk + c8 * 8;
            s16x8 vh = *(const s16x8*)&bT_hi[g];
            s16x8 vl = *(const s16x8*)&bT_lo[g];
            *(s16x8*)&sb_hi[row * LDA + c8 * 8] = vh;
            *(s16x8*)&sb_lo[row * LDA + c8 * 8] = vl;
        }
        __syncthreads();

        int fr = lane & 15, koff = (lane >> 4) * 8;
        s16x8 ah[4], al[4], bh[4], bl[4];
        #pragma unroll
        for (int m = 0; m < 4; m++) {
            int r = wr * 64 + m * 16 + fr;
            ah[m] = *(const s16x8*)&sa_hi[r * LDA + koff];
            al[m] = *(const s16x8*)&sa_lo[r * LDA + koff];
        }
        #pragma unroll
        for (int n = 0; n < 4; n++) {
            int r = wc * 64 + n * 16 + fr;
            bh[n] = *(const s16x8*)&sb_hi[r * LDA + koff];
            bl[n] = *(const s16x8*)&sb_lo[r * LDA + koff];
        }
        #pragma unroll
        for (int m = 0; m < 4; m++)
            #pragma unroll
            for (int n = 0; n < 4; n++) {
                acc[m][n] = __builtin_amdgcn_mfma_f32_16x16x32_bf16(ah[m], bh[n], acc[m][n], 0, 0, 0);
                acc[m][n] = __builtin_amdgcn_mfma_f32_16x16x32_bf16(al[m], bh[n], acc[m][n], 0, 0, 0);
                acc[m][n] = __builtin_amdgcn_mfma_f32_16x16x32_bf16(ah[m], bl[n], acc[m][n], 0, 0, 0);
            }
    }

    // epilogue: tanh (key half) + trunc-split store
    u16* o_hi = is_key ? k_hi : q_hi;
    u16* o_lo = is_key ? k_lo : q_lo;
    int fr = lane & 15, fq = lane >> 4;
    #pragma unroll
    for (int m = 0; m < 4; m++)
        #pragma unroll
        for (int n = 0; n < 4; n++)
            #pragma unroll
            for (int j = 0; j < 4; j++) {
                int grow = m0 + wr * 64 + m * 16 + fq * 4 + j;
                int gcol = bn0 + wc * 64 + n * 16 + fr;
                float v = acc[m][n][j];
                if (is_key) v = fast_tanh(v);
                size_t o = (size_t)grow * 1024 + gcol;
                o_hi[o] = bf16_trunc(v);
                o_lo[o] = bf16_rne(v - bf16_hi_f(v));
            }
}

// ---------------------------------------------------------------------------
// K2: logits[b][s][t] = q[b,s,:] . key[b,t,:]  (split-bf16, causal tiles only)
//     writes raw logits into d region of d_out (lower triangle only)
// ---------------------------------------------------------------------------
__global__ __launch_bounds__(256) void k2_logits(
    const u16* __restrict__ q_hi, const u16* __restrict__ q_lo,
    const u16* __restrict__ k_hi, const u16* __restrict__ k_lo,
    float* __restrict__ dmat)
{
    const int LDA = 40;
    __shared__ u16 sa_hi[128 * 40], sa_lo[128 * 40];
    __shared__ u16 sb_hi[128 * 40], sb_lo[128 * 40];

    int b = blockIdx.y;
    int lin = blockIdx.x;           // 0..135  (st >= tt)
    int st = 0;
    while ((st + 1) * (st + 2) / 2 <= lin) st++;
    int tt = lin - st * (st + 1) / 2;
    int s0 = st * 128, t0 = tt * 128;

    size_t brow = (size_t)b * NSEQ;
    const u16* qh = q_hi + brow * 1024;
    const u16* ql = q_lo + brow * 1024;
    const u16* kh = k_hi + brow * 1024;
    const u16* kl = k_lo + brow * 1024;

    int tid = threadIdx.x;
    int lane = tid & 63;
    int wid = tid >> 6;
    int wr = wid >> 1, wc = wid & 1;

    f32x4 acc[4][4] = {};

    for (int kk = 0; kk < 1024; kk += 32) {
        __syncthreads();
        #pragma unroll
        for (int i = 0; i < 2; i++) {
            int e = i * 256 + tid;
            int row = e >> 2, c8 = e & 3;
            size_t ga = (size_t)(s0 + row) * 1024 + kk + c8 * 8;
            size_t gb = (size_t)(t0 + row) * 1024 + kk + c8 * 8;
            s16x8 vah = *(const s16x8*)&qh[ga];
            s16x8 val = *(const s16x8*)&ql[ga];
            s16x8 vbh = *(const s16x8*)&kh[gb];
            s16x8 vbl = *(const s16x8*)&kl[gb];
            int l = row * LDA + c8 * 8;
            *(s16x8*)&sa_hi[l] = vah;
            *(s16x8*)&sa_lo[l] = val;
            *(s16x8*)&sb_hi[l] = vbh;
            *(s16x8*)&sb_lo[l] = vbl;
        }
        __syncthreads();

        int fr = lane & 15, koff = (lane >> 4) * 8;
        s16x8 ah[4], al[4], bh[4], bl[4];
        #pragma unroll
        for (int m = 0; m < 4; m++) {
            int r = wr * 64 + m * 16 + fr;
            ah[m] = *(const s16x8*)&sa_hi[r * LDA + koff];
            al[m] = *(const s16x8*)&sa_lo[r * LDA + koff];
        }
        #pragma unroll
        for (int n = 0; n < 4; n++) {
            int r = wc * 64 + n * 16 + fr;
            bh[n] = *(const s16x8*)&sb_hi[r * LDA + koff];
            bl[n] = *(const s16x8*)&sb_lo[r * LDA + koff];
        }
        #pragma unroll
        for (int m = 0; m < 4; m++)
            #pragma unroll
            for (int n = 0; n < 4; n++) {
                acc[m][n] = __builtin_amdgcn_mfma_f32_16x16x32_bf16(ah[m], bh[n], acc[m][n], 0, 0, 0);
                acc[m][n] = __builtin_amdgcn_mfma_f32_16x16x32_bf16(al[m], bh[n], acc[m][n], 0, 0, 0);
                acc[m][n] = __builtin_amdgcn_mfma_f32_16x16x32_bf16(ah[m], bl[n], acc[m][n], 0, 0, 0);
            }
    }

    float* db = dmat + (size_t)b * NSEQ * NSEQ;
    int fr = lane & 15, fq = lane >> 4;
    #pragma unroll
    for (int m = 0; m < 4; m++)
        #pragma unroll
        for (int n = 0; n < 4; n++)
            #pragma unroll
            for (int j = 0; j < 4; j++) {
                int s = s0 + wr * 64 + m * 16 + fq * 4 + j;
                int t = t0 + wc * 64 + n * 16 + fr;
                if (t <= s) db[(size_t)s * NSEQ + t] = acc[m][n][j];
            }
}

// ---------------------------------------------------------------------------
// K3: row-wise causal softmax over dmat, in place. Writes zeros above diag.
// ---------------------------------------------------------------------------
__global__ __launch_bounds__(256) void k3_softmax(float* __restrict__ dmat)
{
    __shared__ float redm[4];
    __shared__ float reds[4];
    int rowid = blockIdx.x;             // 0..32767  (b*2048 + s)
    int s = rowid & (NSEQ - 1);
    float* row = dmat + (size_t)rowid * NSEQ;
    int tid = threadIdx.x;
    int lane = tid & 63, w = tid >> 6;

    float v[8];
    #pragma unroll
    for (int i = 0; i < 8; i++) {
        int t = i * 256 + tid;
        v[i] = (t <= s) ? row[t] : -INFINITY;
    }
    float m = -INFINITY;
    #pragma unroll
    for (int i = 0; i < 8; i++) m = fmaxf(m, v[i]);
    #pragma unroll
    for (int off = 32; off > 0; off >>= 1) m = fmaxf(m, __shfl_xor(m, off));
    if (lane == 0) redm[w] = m;
    __syncthreads();
    m = fmaxf(fmaxf(redm[0], redm[1]), fmaxf(redm[2], redm[3]));

    float sum = 0.f;
    float ev[8];
    #pragma unroll
    for (int i = 0; i < 8; i++) {
        int t = i * 256 + tid;
        ev[i] = (t <= s) ? __expf(v[i] - m) : 0.f;
        sum += ev[i];
    }
    #pragma unroll
    for (int off = 32; off > 0; off >>= 1) sum += __shfl_xor(sum, off);
    if (lane == 0) reds[w] = sum;
    __syncthreads();
    sum = reds[0] + reds[1] + reds[2] + reds[3];
    float inv = 1.0f / sum;
    #pragma unroll
    for (int i = 0; i < 8; i++) {
        int t = i * 256 + tid;
        row[t] = (t <= s) ? ev[i] * inv : 0.0f;
    }
}

// ---------------------------------------------------------------------------
// K4: a = d @ x  (plain bf16; K-loop truncated at diagonal)
// ---------------------------------------------------------------------------
__global__ __launch_bounds__(256) void k4_av(
    const float* __restrict__ dmat,
    const u16* __restrict__ xT,
    float* __restrict__ aout)
{
    const int LDA = 40;
    __shared__ u16 sa[128 * 40];
    __shared__ u16 sb[128 * 40];

    int n0 = blockIdx.x * 128;      // h tile (0..7)
    int s0 = blockIdx.y * 128;      // s tile (0..15)
    int b = blockIdx.z;

    const float* db = dmat + (size_t)b * NSEQ * NSEQ;
    const u16* xTb = xT + (size_t)b * NHID * NSEQ;

    int tid = threadIdx.x;
    int lane = tid & 63;
    int wid = tid >> 6;
    int wr = wid >> 1, wc = wid & 1;

    f32x4 acc[4][4] = {};
    int kmax = s0 + 128;            // d[s][t] == 0 for t > s

    for (int kk = 0; kk < kmax; kk += 32) {
        __syncthreads();
        // stage A: d[s0..+128][kk..+32] f32 -> bf16 (RNE)
        #pragma unroll
        for (int i = 0; i < 4; i++) {
            int e = i * 256 + tid;
            int row = e >> 3, c4 = e & 7;
            float4 v = *(const float4*)&db[(size_t)(s0 + row) * NSEQ + kk + c4 * 4];
            u16x4 hv;
            hv[0] = bf16_rne(v.x); hv[1] = bf16_rne(v.y);
            hv[2] = bf16_rne(v.z); hv[3] = bf16_rne(v.w);
            *(u16x4*)&sa[row * LDA + c4 * 4] = hv;
        }
        // stage B: xT[n0..+128][kk..+32] bf16
        #pragma unroll
        for (int i = 0; i < 2; i++) {
            int e = i * 256 + tid;
            int row = e >> 2, c8 = e & 3;
            s16x8 vv = *(const s16x8*)&xTb[(size_t)(n0 + row) * NSEQ + kk + c8 * 8];
            *(s16x8*)&sb[row * LDA + c8 * 8] = vv;
        }
        __syncthreads();

        int fr = lane & 15, koff = (lane >> 4) * 8;
        s16x8 af[4], bfr[4];
        #pragma unroll
        for (int m = 0; m < 4; m++)
            af[m] = *(const s16x8*)&sa[(wr * 64 + m * 16 + fr) * LDA + koff];
        #pragma unroll
        for (int n = 0; n < 4; n++)
            bfr[n] = *(const s16x8*)&sb[(wc * 64 + n * 16 + fr) * LDA + koff];
        #pragma unroll
        for (int m = 0; m < 4; m++)
            #pragma unroll
            for (int n = 0; n < 4; n++)
                acc[m][n] = __builtin_amdgcn_mfma_f32_16x16x32_bf16(af[m], bfr[n], acc[m][n], 0, 0, 0);
    }

    float* ab = aout + (size_t)b * NSEQ * NHID;
    int fr = lane & 15, fq = lane >> 4;
    #pragma unroll
    for (int m = 0; m < 4; m++)
        #pragma unroll
        for (int n = 0; n < 4; n++)
            #pragma unroll
            for (int j = 0; j < 4; j++) {
                int s = s0 + wr * 64 + m * 16 + fq * 4 + j;
                int h = n0 + wc * 64 + n * 16 + fr;
                ab[(size_t)s * 1024 + h] = acc[m][n][j];
            }
}

// ---------------------------------------------------------------------------
extern "C" void kernel_launch(void* const* d_in, const int* in_sizes, int n_in,
                              void* d_out, int out_size, void* d_ws, size_t ws_size,
                              hipStream_t stream)
{
    const float* x     = (const float*)d_in[0];
    const float* w_a   = (const float*)d_in[1];
    const float* query = (const float*)d_in[2];

    float* aout = (float*)d_out;                         // [16][2048][1024]
    float* dmat = aout + (size_t)NBATCH * NSEQ * NHID;   // [16][2048][2048]

    // workspace layout (total ~344 MB)
    const size_t NQK = (size_t)MALL * NATT;              // 33,554,432
    char* p = (char*)d_ws;
    u16* q_hi = (u16*)p; p += NQK * 2;
    u16* q_lo = (u16*)p; p += NQK * 2;
    u16* k_hi = (u16*)p; p += NQK * 2;
    u16* k_lo = (u16*)p; p += NQK * 2;
    u16* xT   = (u16*)p; p += NQK * 2;
    u16* waT_hi = (u16*)p; p += (size_t)NHID * NATT * 2;
    u16* waT_lo = (u16*)p; p += (size_t)NHID * NATT * 2;
    u16* quT_hi = (u16*)p; p += (size_t)NHID * NATT * 2;
    u16* quT_lo = (u16*)p; p += (size_t)NHID * NATT * 2;
    (void)ws_size; (void)in_sizes; (void)n_in; (void)out_size;

    wsplit_kernel<<<dim3(4096), 256, 0, stream>>>(w_a, query, waT_hi, waT_lo, quT_hi, quT_lo);
    xT_kernel<<<dim3(32, 16, 16), 256, 0, stream>>>(x, xT);
    k1_gemm<<<dim3(16, 256), 256, 0, stream>>>(x, waT_hi, waT_lo, quT_hi, quT_lo,
                                               k_hi, k_lo, q_hi, q_lo);
    k2_logits<<<dim3(136, 16), 256, 0, stream>>>(q_hi, q_lo, k_hi, k_lo, dmat);
    k3_softmax<<<dim3(32768), 256, 0, stream>>>(dmat);
    k4_av<<<dim3(8, 16, 16), 256, 0, stream>>>(dmat, xT, aout);
}

// Round 2
// 1004.633 us; speedup vs baseline: 1.1869x; 1.1869x over previous
//
#include <hip/hip_runtime.h>

typedef short s16x8 __attribute__((ext_vector_type(8)));
typedef float f32x4 __attribute__((ext_vector_type(4)));
typedef unsigned short u16;
typedef u16 u16x4 __attribute__((ext_vector_type(4)));
typedef u16 u16x8 __attribute__((ext_vector_type(8)));

#define NBATCH 16
#define NSEQ   2048
#define NHID   1024
#define NATT   1024
#define MALL   (NBATCH * NSEQ)   // 32768

__device__ __forceinline__ float bf16_hi_f(float x) {
    return __uint_as_float(__float_as_uint(x) & 0xffff0000u);
}
__device__ __forceinline__ u16 bf16_trunc(float x) {
    return (u16)(__float_as_uint(x) >> 16);
}
__device__ __forceinline__ u16 bf16_rne(float x) {
    unsigned u = __float_as_uint(x);
    unsigned r = u + 0x7fffu + ((u >> 16) & 1u);
    return (u16)(r >> 16);
}
__device__ __forceinline__ float fast_tanh(float x) {
    float e = __expf(2.0f * x);
    return 1.0f - 2.0f / (e + 1.0f);
}

// async global->LDS, 16B per lane; dest = wave-uniform base + lane*16
#define GLOAD16(g, l) __builtin_amdgcn_global_load_lds(                         \
    (const __attribute__((address_space(1))) unsigned int*)(g),                 \
    (__attribute__((address_space(3))) unsigned int*)(l), 16, 0, 0)

// ---------------------------------------------------------------------------
// P1: transpose + split w_a and query:  wT_*[n][h] = split(w[h][n])
// ---------------------------------------------------------------------------
__global__ __launch_bounds__(256) void wsplit_kernel(
    const float* __restrict__ wa, const float* __restrict__ qu,
    u16* __restrict__ waT_hi, u16* __restrict__ waT_lo,
    u16* __restrict__ quT_hi, u16* __restrict__ quT_lo)
{
    int idx = blockIdx.x * 256 + threadIdx.x;   // 0 .. 1M-1
    int h = idx >> 10, n = idx & 1023;
    float va = wa[idx];
    float vq = qu[idx];
    int o = n * 1024 + h;
    waT_hi[o] = bf16_trunc(va);
    waT_lo[o] = bf16_rne(va - bf16_hi_f(va));
    quT_hi[o] = bf16_trunc(vq);
    quT_lo[o] = bf16_rne(vq - bf16_hi_f(vq));
}

// ---------------------------------------------------------------------------
// P2: read x once ->  xT[b][h][t] (bf16, for K4 B)  +  x_hi/x_lo (split, K1 A)
// ---------------------------------------------------------------------------
__global__ __launch_bounds__(256) void xprep_kernel(
    const float* __restrict__ x, u16* __restrict__ xT,
    u16* __restrict__ x_hi, u16* __restrict__ x_lo)
{
    __shared__ u16 tile[64][65];
    int b = blockIdx.z;
    int t0 = blockIdx.x * 64;
    int h0 = blockIdx.y * 64;
    const float* xb = x + (size_t)b * NSEQ * NHID;
    int tid = threadIdx.x;
    #pragma unroll
    for (int i = 0; i < 16; i++) {
        int e = i * 256 + tid;
        int tl = e >> 6, hl = e & 63;
        float v = xb[(size_t)(t0 + tl) * NHID + h0 + hl];
        tile[tl][hl] = bf16_rne(v);
        size_t gi = (size_t)(b * NSEQ + t0 + tl) * NHID + h0 + hl;
        x_hi[gi] = bf16_trunc(v);
        x_lo[gi] = bf16_rne(v - bf16_hi_f(v));
    }
    __syncthreads();
    u16* xTb = xT + (size_t)b * NHID * NSEQ;
    #pragma unroll
    for (int i = 0; i < 16; i++) {
        int e = i * 256 + tid;
        int hl = e >> 6, tl = e & 63;
        xTb[(size_t)(h0 + hl) * NSEQ + t0 + tl] = tile[tl][hl];
    }
}

// ---------------------------------------------------------------------------
// K1: key = tanh(x @ w_a), q = x @ query  — split-bf16 MFMA, gload_lds staging
// ---------------------------------------------------------------------------
__global__ __launch_bounds__(256) void k1_gemm(
    const u16* __restrict__ x_hi, const u16* __restrict__ x_lo,
    const u16* __restrict__ waT_hi, const u16* __restrict__ waT_lo,
    const u16* __restrict__ quT_hi, const u16* __restrict__ quT_lo,
    u16* __restrict__ k_hi, u16* __restrict__ k_lo,
    u16* __restrict__ q_hi, u16* __restrict__ q_lo)
{
    __shared__ u16 sa_hi[128 * 32], sa_lo[128 * 32];
    __shared__ u16 sb_hi[128 * 32], sb_lo[128 * 32];

    // XCD-chunked swizzle (4096 blocks, %8==0): n-tile fast within chunk
    int wg = blockIdx.x;
    int nid = (wg & 7) * 512 + (wg >> 3);
    int n0 = (nid & 15) * 128;
    int m0 = (nid >> 4) * 128;
    bool is_key = (n0 < 1024);
    const u16* bh_src = is_key ? waT_hi : quT_hi;
    const u16* bl_src = is_key ? waT_lo : quT_lo;
    int bn0 = is_key ? n0 : (n0 - 1024);

    int tid = threadIdx.x;
    int lane = tid & 63;
    int w = tid >> 6;
    int wr = w >> 1, wc = w & 1;

    // staging decomposition: wave w, lane l -> row = r*64 + w*16 + (l>>2),
    // LDS slot' = l&3, global slot = slot' ^ ((row>>1)&3) = (l&3)^((l>>3)&3)
    int srow = w * 16 + (lane >> 2);
    int sslot = ((lane & 3) ^ ((lane >> 3) & 3)) * 8;

    const u16* pah = x_hi + (size_t)(m0 + srow) * 1024 + sslot;
    const u16* pal = x_lo + (size_t)(m0 + srow) * 1024 + sslot;
    const u16* pbh = bh_src + (size_t)(bn0 + srow) * 1024 + sslot;
    const u16* pbl = bl_src + (size_t)(bn0 + srow) * 1024 + sslot;
    u16* dah0 = &sa_hi[(w * 16) * 32];      u16* dah1 = &sa_hi[(64 + w * 16) * 32];
    u16* dal0 = &sa_lo[(w * 16) * 32];      u16* dal1 = &sa_lo[(64 + w * 16) * 32];
    u16* dbh0 = &sb_hi[(w * 16) * 32];      u16* dbh1 = &sb_hi[(64 + w * 16) * 32];
    u16* dbl0 = &sb_lo[(w * 16) * 32];      u16* dbl1 = &sb_lo[(64 + w * 16) * 32];
    const size_t R64 = (size_t)64 * 1024;

    // fragment read: row = rb+fr, lds slot = sg ^ ((fr>>1)&3)
    int fr = lane & 15, sg = lane >> 4;
    int rsl = (sg ^ ((fr >> 1) & 3)) * 8;

    f32x4 acc[4][4] = {};

    for (int kk = 0; kk < 1024; kk += 32) {
        __syncthreads();
        GLOAD16(pah + kk, dah0); GLOAD16(pah + kk + R64, dah1);
        GLOAD16(pal + kk, dal0); GLOAD16(pal + kk + R64, dal1);
        GLOAD16(pbh + kk, dbh0); GLOAD16(pbh + kk + R64, dbh1);
        GLOAD16(pbl + kk, dbl0); GLOAD16(pbl + kk + R64, dbl1);
        __syncthreads();

        s16x8 ah[4], al[4], bh[4], bl[4];
        #pragma unroll
        for (int m = 0; m < 4; m++) {
            int rb = wr * 64 + m * 16 + fr;
            ah[m] = *(const s16x8*)&sa_hi[rb * 32 + rsl];
            al[m] = *(const s16x8*)&sa_lo[rb * 32 + rsl];
        }
        #pragma unroll
        for (int n = 0; n < 4; n++) {
            int rb = wc * 64 + n * 16 + fr;
            bh[n] = *(const s16x8*)&sb_hi[rb * 32 + rsl];
            bl[n] = *(const s16x8*)&sb_lo[rb * 32 + rsl];
        }
        #pragma unroll
        for (int m = 0; m < 4; m++)
            #pragma unroll
            for (int n = 0; n < 4; n++) {
                acc[m][n] = __builtin_amdgcn_mfma_f32_16x16x32_bf16(ah[m], bh[n], acc[m][n], 0, 0, 0);
                acc[m][n] = __builtin_amdgcn_mfma_f32_16x16x32_bf16(al[m], bh[n], acc[m][n], 0, 0, 0);
                acc[m][n] = __builtin_amdgcn_mfma_f32_16x16x32_bf16(ah[m], bl[n], acc[m][n], 0, 0, 0);
            }
    }

    u16* o_hi = is_key ? k_hi : q_hi;
    u16* o_lo = is_key ? k_lo : q_lo;
    int fq = lane >> 4;
    #pragma unroll
    for (int m = 0; m < 4; m++)
        #pragma unroll
        for (int n = 0; n < 4; n++)
            #pragma unroll
            for (int j = 0; j < 4; j++) {
                int grow = m0 + wr * 64 + m * 16 + fq * 4 + j;
                int gcol = bn0 + wc * 64 + n * 16 + fr;
                float v = acc[m][n][j];
                if (is_key) v = fast_tanh(v);
                size_t o = (size_t)grow * 1024 + gcol;
                o_hi[o] = bf16_trunc(v);
                o_lo[o] = bf16_rne(v - bf16_hi_f(v));
            }
}

// ---------------------------------------------------------------------------
// K2: logits[b][s][t] = q[b,s,:] . key[b,t,:]  (split-bf16, causal tiles only)
// ---------------------------------------------------------------------------
__global__ __launch_bounds__(256) void k2_logits(
    const u16* __restrict__ q_hi, const u16* __restrict__ q_lo,
    const u16* __restrict__ k_hi, const u16* __restrict__ k_lo,
    float* __restrict__ dmat)
{
    __shared__ u16 sa_hi[128 * 32], sa_lo[128 * 32];
    __shared__ u16 sb_hi[128 * 32], sb_lo[128 * 32];

    // 2176 blocks = 8*272; within chunk: lin fast (shares batch + q-rows)
    int wg = blockIdx.x;
    int nid = (wg & 7) * 272 + (wg >> 3);
    int b = nid / 136;
    int lin = nid - b * 136;
    int st = 0;
    while ((st + 1) * (st + 2) / 2 <= lin) st++;
    int tt = lin - st * (st + 1) / 2;
    int s0 = st * 128, t0 = tt * 128;

    size_t bbase = (size_t)b * NSEQ * 1024;
    int tid = threadIdx.x;
    int lane = tid & 63;
    int w = tid >> 6;
    int wr = w >> 1, wc = w & 1;

    int srow = w * 16 + (lane >> 2);
    int sslot = ((lane & 3) ^ ((lane >> 3) & 3)) * 8;

    const u16* pah = q_hi + bbase + (size_t)(s0 + srow) * 1024 + sslot;
    const u16* pal = q_lo + bbase + (size_t)(s0 + srow) * 1024 + sslot;
    const u16* pbh = k_hi + bbase + (size_t)(t0 + srow) * 1024 + sslot;
    const u16* pbl = k_lo + bbase + (size_t)(t0 + srow) * 1024 + sslot;
    u16* dah0 = &sa_hi[(w * 16) * 32];      u16* dah1 = &sa_hi[(64 + w * 16) * 32];
    u16* dal0 = &sa_lo[(w * 16) * 32];      u16* dal1 = &sa_lo[(64 + w * 16) * 32];
    u16* dbh0 = &sb_hi[(w * 16) * 32];      u16* dbh1 = &sb_hi[(64 + w * 16) * 32];
    u16* dbl0 = &sb_lo[(w * 16) * 32];      u16* dbl1 = &sb_lo[(64 + w * 16) * 32];
    const size_t R64 = (size_t)64 * 1024;

    int fr = lane & 15, sg = lane >> 4;
    int rsl = (sg ^ ((fr >> 1) & 3)) * 8;

    f32x4 acc[4][4] = {};

    for (int kk = 0; kk < 1024; kk += 32) {
        __syncthreads();
        GLOAD16(pah + kk, dah0); GLOAD16(pah + kk + R64, dah1);
        GLOAD16(pal + kk, dal0); GLOAD16(pal + kk + R64, dal1);
        GLOAD16(pbh + kk, dbh0); GLOAD16(pbh + kk + R64, dbh1);
        GLOAD16(pbl + kk, dbl0); GLOAD16(pbl + kk + R64, dbl1);
        __syncthreads();

        s16x8 ah[4], al[4], bh[4], bl[4];
        #pragma unroll
        for (int m = 0; m < 4; m++) {
            int rb = wr * 64 + m * 16 + fr;
            ah[m] = *(const s16x8*)&sa_hi[rb * 32 + rsl];
            al[m] = *(const s16x8*)&sa_lo[rb * 32 + rsl];
        }
        #pragma unroll
        for (int n = 0; n < 4; n++) {
            int rb = wc * 64 + n * 16 + fr;
            bh[n] = *(const s16x8*)&sb_hi[rb * 32 + rsl];
            bl[n] = *(const s16x8*)&sb_lo[rb * 32 + rsl];
        }
        #pragma unroll
        for (int m = 0; m < 4; m++)
            #pragma unroll
            for (int n = 0; n < 4; n++) {
                acc[m][n] = __builtin_amdgcn_mfma_f32_16x16x32_bf16(ah[m], bh[n], acc[m][n], 0, 0, 0);
                acc[m][n] = __builtin_amdgcn_mfma_f32_16x16x32_bf16(al[m], bh[n], acc[m][n], 0, 0, 0);
                acc[m][n] = __builtin_amdgcn_mfma_f32_16x16x32_bf16(ah[m], bl[n], acc[m][n], 0, 0, 0);
            }
    }

    float* db = dmat + (size_t)b * NSEQ * NSEQ;
    int fq = lane >> 4;
    #pragma unroll
    for (int m = 0; m < 4; m++)
        #pragma unroll
        for (int n = 0; n < 4; n++)
            #pragma unroll
            for (int j = 0; j < 4; j++) {
                int s = s0 + wr * 64 + m * 16 + fq * 4 + j;
                int t = t0 + wc * 64 + n * 16 + fr;
                if (t <= s) db[(size_t)s * NSEQ + t] = acc[m][n][j];
            }
}

// ---------------------------------------------------------------------------
// K3: row-wise causal softmax, in place; also emit bf16 copy for K4.
// ---------------------------------------------------------------------------
__global__ __launch_bounds__(256) void k3_softmax(
    float* __restrict__ dmat, u16* __restrict__ d_bf16)
{
    __shared__ float redm[4];
    __shared__ float reds[4];
    int rowid = blockIdx.x;             // b*2048 + s
    int s = rowid & (NSEQ - 1);
    float* row = dmat + (size_t)rowid * NSEQ;
    int tid = threadIdx.x;
    int lane = tid & 63, w = tid >> 6;
    int t0 = tid * 8;

    float v[8];
    if (t0 <= s) {
        float4 a = *(const float4*)&row[t0];
        float4 c = *(const float4*)&row[t0 + 4];
        v[0] = a.x; v[1] = a.y; v[2] = a.z; v[3] = a.w;
        v[4] = c.x; v[5] = c.y; v[6] = c.z; v[7] = c.w;
        #pragma unroll
        for (int i = 0; i < 8; i++) if (t0 + i > s) v[i] = -INFINITY;
    } else {
        #pragma unroll
        for (int i = 0; i < 8; i++) v[i] = -INFINITY;
    }

    float m = -INFINITY;
    #pragma unroll
    for (int i = 0; i < 8; i++) m = fmaxf(m, v[i]);
    #pragma unroll
    for (int off = 32; off > 0; off >>= 1) m = fmaxf(m, __shfl_xor(m, off));
    if (lane == 0) redm[w] = m;
    __syncthreads();
    m = fmaxf(fmaxf(redm[0], redm[1]), fmaxf(redm[2], redm[3]));

    float sum = 0.f;
    float ev[8];
    #pragma unroll
    for (int i = 0; i < 8; i++) {
        ev[i] = (t0 + i <= s) ? __expf(v[i] - m) : 0.f;
        sum += ev[i];
    }
    #pragma unroll
    for (int off = 32; off > 0; off >>= 1) sum += __shfl_xor(sum, off);
    if (lane == 0) reds[w] = sum;
    __syncthreads();
    sum = reds[0] + reds[1] + reds[2] + reds[3];
    float inv = 1.0f / sum;

    float4 o0, o1;
    o0.x = ev[0] * inv; o0.y = ev[1] * inv; o0.z = ev[2] * inv; o0.w = ev[3] * inv;
    o1.x = ev[4] * inv; o1.y = ev[5] * inv; o1.z = ev[6] * inv; o1.w = ev[7] * inv;
    *(float4*)&row[t0] = o0;
    *(float4*)&row[t0 + 4] = o1;
    u16x8 bv;
    bv[0] = bf16_rne(o0.x); bv[1] = bf16_rne(o0.y); bv[2] = bf16_rne(o0.z); bv[3] = bf16_rne(o0.w);
    bv[4] = bf16_rne(o1.x); bv[5] = bf16_rne(o1.y); bv[6] = bf16_rne(o1.z); bv[7] = bf16_rne(o1.w);
    *(u16x8*)&d_bf16[(size_t)rowid * NSEQ + t0] = bv;
}

// ---------------------------------------------------------------------------
// K4: a = d @ x  (bf16 MFMA, gload_lds staging, K truncated at diagonal)
// ---------------------------------------------------------------------------
__global__ __launch_bounds__(256) void k4_av(
    const u16* __restrict__ d_bf16,
    const u16* __restrict__ xT,
    float* __restrict__ aout)
{
    __shared__ u16 sa[128 * 32];
    __shared__ u16 sb[128 * 32];

    // 2048 blocks = 8*256; n fast within chunk (shares d s-tile)
    int wg = blockIdx.x;
    int nid = (wg & 7) * 256 + (wg >> 3);
    int n0 = (nid & 7) * 128;
    int s0 = ((nid >> 3) & 15) * 128;
    int b = nid >> 7;

    int tid = threadIdx.x;
    int lane = tid & 63;
    int w = tid >> 6;
    int wr = w >> 1, wc = w & 1;

    int srow = w * 16 + (lane >> 2);
    int sslot = ((lane & 3) ^ ((lane >> 3) & 3)) * 8;

    const u16* pa = d_bf16 + (size_t)(b * NSEQ + s0 + srow) * NSEQ + sslot;
    const u16* pb = xT + ((size_t)b * NHID + n0 + srow) * NSEQ + sslot;
    u16* da0 = &sa[(w * 16) * 32];  u16* da1 = &sa[(64 + w * 16) * 32];
    u16* db0 = &sb[(w * 16) * 32];  u16* db1 = &sb[(64 + w * 16) * 32];
    const size_t R64 = (size_t)64 * NSEQ;

    int fr = lane & 15, sg = lane >> 4;
    int rsl = (sg ^ ((fr >> 1) & 3)) * 8;

    f32x4 acc[4][4] = {};
    int kmax = s0 + 128;            // d[s][t] == 0 for t > s

    for (int kk = 0; kk < kmax; kk += 32) {
        __syncthreads();
        GLOAD16(pa + kk, da0); GLOAD16(pa + kk + R64, da1);
        GLOAD16(pb + kk, db0); GLOAD16(pb + kk + R64, db1);
        __syncthreads();

        s16x8 af[4], bf[4];
        #pragma unroll
        for (int m = 0; m < 4; m++)
            af[m] = *(const s16x8*)&sa[(wr * 64 + m * 16 + fr) * 32 + rsl];
        #pragma unroll
        for (int n = 0; n < 4; n++)
            bf[n] = *(const s16x8*)&sb[(wc * 64 + n * 16 + fr) * 32 + rsl];
        #pragma unroll
        for (int m = 0; m < 4; m++)
            #pragma unroll
            for (int n = 0; n < 4; n++)
                acc[m][n] = __builtin_amdgcn_mfma_f32_16x16x32_bf16(af[m], bf[n], acc[m][n], 0, 0, 0);
    }

    float* ab = aout + (size_t)b * NSEQ * NHID;
    int fq = lane >> 4;
    #pragma unroll
    for (int m = 0; m < 4; m++)
        #pragma unroll
        for (int n = 0; n < 4; n++)
            #pragma unroll
            for (int j = 0; j < 4; j++) {
                int s = s0 + wr * 64 + m * 16 + fq * 4 + j;
                int h = n0 + wc * 64 + n * 16 + fr;
                ab[(size_t)s * NHID + h] = acc[m][n][j];
            }
}

// ---------------------------------------------------------------------------
extern "C" void kernel_launch(void* const* d_in, const int* in_sizes, int n_in,
                              void* d_out, int out_size, void* d_ws, size_t ws_size,
                              hipStream_t stream)
{
    const float* x     = (const float*)d_in[0];
    const float* w_a   = (const float*)d_in[1];
    const float* query = (const float*)d_in[2];

    float* aout = (float*)d_out;                         // [16][2048][1024]
    float* dmat = aout + (size_t)NBATCH * NSEQ * NHID;   // [16][2048][2048]

    const size_t NQK = (size_t)MALL * NATT;              // 33,554,432 elems
    char* p = (char*)d_ws;
    u16* q_hi = (u16*)p; p += NQK * 2;
    u16* q_lo = (u16*)p; p += NQK * 2;
    u16* k_hi = (u16*)p; p += NQK * 2;
    u16* k_lo = (u16*)p; p += NQK * 2;
    u16* xT   = (u16*)p; p += NQK * 2;
    u16* x_hi = (u16*)p; p += NQK * 2;                   // dead after K1
    u16* x_lo = (u16*)p; p += NQK * 2;                   // dead after K1
    u16* d_bf16 = x_hi;                                  // aliases x_hi+x_lo (134 MB)
    u16* waT_hi = (u16*)p; p += (size_t)NHID * NATT * 2;
    u16* waT_lo = (u16*)p; p += (size_t)NHID * NATT * 2;
    u16* quT_hi = (u16*)p; p += (size_t)NHID * NATT * 2;
    u16* quT_lo = (u16*)p; p += (size_t)NHID * NATT * 2;
    (void)ws_size; (void)in_sizes; (void)n_in; (void)out_size;

    wsplit_kernel<<<dim3(4096), 256, 0, stream>>>(w_a, query, waT_hi, waT_lo, quT_hi, quT_lo);
    xprep_kernel<<<dim3(32, 16, 16), 256, 0, stream>>>(x, xT, x_hi, x_lo);
    k1_gemm<<<dim3(4096), 256, 0, stream>>>(x_hi, x_lo, waT_hi, waT_lo, quT_hi, quT_lo,
                                            k_hi, k_lo, q_hi, q_lo);
    k2_logits<<<dim3(2176), 256, 0, stream>>>(q_hi, q_lo, k_hi, k_lo, dmat);
    k3_softmax<<<dim3(32768), 256, 0, stream>>>(dmat, d_bf16);
    k4_av<<<dim3(2048), 256, 0, stream>>>(d_bf16, xT, aout);
}

// Round 3
// 900.287 us; speedup vs baseline: 1.3245x; 1.1159x over previous
//
#include <hip/hip_runtime.h>

typedef short s16x8 __attribute__((ext_vector_type(8)));
typedef float f32x4 __attribute__((ext_vector_type(4)));
typedef unsigned short u16;
typedef u16 u16x8 __attribute__((ext_vector_type(8)));

#define NBATCH 16
#define NSEQ   2048
#define NHID   1024
#define NATT   1024
#define MALL   (NBATCH * NSEQ)   // 32768

__device__ __forceinline__ float bf16_hi_f(float x) {
    return __uint_as_float(__float_as_uint(x) & 0xffff0000u);
}
__device__ __forceinline__ u16 bf16_trunc(float x) {
    return (u16)(__float_as_uint(x) >> 16);
}
__device__ __forceinline__ u16 bf16_rne(float x) {
    unsigned u = __float_as_uint(x);
    unsigned r = u + 0x7fffu + ((u >> 16) & 1u);
    return (u16)(r >> 16);
}
__device__ __forceinline__ float fast_tanh(float x) {
    float e = __expf(2.0f * x);
    return 1.0f - 2.0f / (e + 1.0f);
}

#define GLOAD16(g, l) __builtin_amdgcn_global_load_lds(                         \
    (const __attribute__((address_space(1))) unsigned int*)(g),                 \
    (__attribute__((address_space(3))) unsigned int*)(l), 16, 0, 0)

// ===========================================================================
// 256x256 8-phase split-bf16 GEMM core.
// Split layout: row-major [rows][32 kt][64] u16, cols 0-31 = bf16-hi of
// k=32*kt..+31, cols 32-63 = bf16-lo. LDS per buffer: A[256][64] + B[256][64]
// = 64KB; 2 buffers = 128KB (dynamic). Slot swizzle: 16B slot ^= (row&7),
// applied on global source (involution) and on ds_read address.
// ===========================================================================

#define RD_A(C,MH,m,S) (*(const s16x8*)&lds[(C)*32768 + ((MH)*128 + wr*64 + (m)*16 + fr)*64 + (S)])
#define RD_B(C,NH,n,S) (*(const s16x8*)&lds[(C)*32768 + 16384 + ((NH)*128 + wc*32 + (n)*16 + fr)*64 + (S)])

#define SRC_(REG) ((REG) ? Bptr : Aptr)
#define ROW_(REG) ((REG) ? Brow0 : Arow0)

// stage half-tile H (128 rows) of region REG (0=A,1=B), K-tile T, into buf C
#define STAGE(C, REG, H, T) do {                                               \
    int rg_ = ROW_(REG) + (H)*128 + w*8 + (l>>3);                              \
    const u16* s_ = SRC_(REG) + (size_t)rg_*2048 + (size_t)(T)*64              \
                    + (((l&7)^(rg_&7))*8);                                     \
    u16* d_ = &lds[(C)*32768 + (REG)*16384 + ((H)*128 + w*8)*64];              \
    GLOAD16(s_, d_);                                                           \
    GLOAD16(s_ + (size_t)64*2048, d_ + 64*64);                                 \
} while(0)

#define NOPS ((void)0)
#define VMW4 asm volatile("s_waitcnt vmcnt(4)" ::: "memory");
#define VMW0 asm volatile("s_waitcnt vmcnt(0)" ::: "memory");

#define MFMA3(dst, ah_, al_, bh_, bl_)                                         \
    dst = __builtin_amdgcn_mfma_f32_16x16x32_bf16(ah_, bh_, dst, 0, 0, 0);     \
    dst = __builtin_amdgcn_mfma_f32_16x16x32_bf16(al_, bh_, dst, 0, 0, 0);     \
    dst = __builtin_amdgcn_mfma_f32_16x16x32_bf16(ah_, bl_, dst, 0, 0, 0);

#define PH_TAIL(MH, NH, bh0_, bl0_, bh1_, bl1_, WAITS)                         \
    __builtin_amdgcn_s_barrier();                                              \
    asm volatile("s_waitcnt lgkmcnt(0)" ::: "memory");                         \
    __builtin_amdgcn_sched_barrier(0);                                         \
    __builtin_amdgcn_s_setprio(1);                                             \
    MFMA3(acc[MH][NH][0][0], a0h, a0l, bh0_, bl0_)                             \
    MFMA3(acc[MH][NH][0][1], a0h, a0l, bh1_, bl1_)                             \
    MFMA3(acc[MH][NH][1][0], a1h, a1l, bh0_, bl0_)                             \
    MFMA3(acc[MH][NH][1][1], a1h, a1l, bh1_, bl1_)                             \
    MFMA3(acc[MH][NH][2][0], a2h, a2l, bh0_, bl0_)                             \
    MFMA3(acc[MH][NH][2][1], a2h, a2l, bh1_, bl1_)                             \
    MFMA3(acc[MH][NH][3][0], a3h, a3l, bh0_, bl0_)                             \
    MFMA3(acc[MH][NH][3][1], a3h, a3l, bh1_, bl1_)                             \
    __builtin_amdgcn_s_setprio(0);                                             \
    WAITS                                                                      \
    __builtin_amdgcn_s_barrier();

// 4 phases per K-tile: (mh,nh) = (0,0),(0,1),(1,0),(1,1).
// A-frags loaded at p0/p2 reused across nh; B-frags loaded p0/p1 reused across mh.
#define TILE(C, ST0, ST1, ST2, ST3, W3) {                                      \
    a0h = RD_A(C,0,0,sHi); a0l = RD_A(C,0,0,sLo);                              \
    a1h = RD_A(C,0,1,sHi); a1l = RD_A(C,0,1,sLo);                              \
    a2h = RD_A(C,0,2,sHi); a2l = RD_A(C,0,2,sLo);                              \
    a3h = RD_A(C,0,3,sHi); a3l = RD_A(C,0,3,sLo);                              \
    p0h = RD_B(C,0,0,sHi); p0l = RD_B(C,0,0,sLo);                              \
    p1h = RD_B(C,0,1,sHi); p1l = RD_B(C,0,1,sLo);                              \
    ST0;                                                                       \
    PH_TAIL(0,0, p0h,p0l,p1h,p1l, )                                            \
    q0h = RD_B(C,1,0,sHi); q0l = RD_B(C,1,0,sLo);                              \
    q1h = RD_B(C,1,1,sHi); q1l = RD_B(C,1,1,sLo);                              \
    ST1;                                                                       \
    PH_TAIL(0,1, q0h,q0l,q1h,q1l, )                                            \
    a0h = RD_A(C,1,0,sHi); a0l = RD_A(C,1,0,sLo);                              \
    a1h = RD_A(C,1,1,sHi); a1l = RD_A(C,1,1,sLo);                              \
    a2h = RD_A(C,1,2,sHi); a2l = RD_A(C,1,2,sLo);                              \
    a3h = RD_A(C,1,3,sHi); a3l = RD_A(C,1,3,sLo);                              \
    ST2;                                                                       \
    PH_TAIL(1,0, p0h,p0l,p1h,p1l, )                                            \
    ST3;                                                                       \
    PH_TAIL(1,1, q0h,q0l,q1h,q1l, W3)                                          \
}

__device__ __forceinline__ void gemm_core(
    const u16* __restrict__ Aptr, int Arow0,
    const u16* __restrict__ Bptr, int Brow0,
    u16* lds, f32x4 (&acc)[2][2][4][2])
{
    int tid = threadIdx.x;
    int l = tid & 63, w = tid >> 6;          // lane, wave(0..7)
    int wr = w >> 2, wc = w & 3;             // 2M x 4N wave grid
    int fr = l & 15, sg = l >> 4;
    int sHi = (sg ^ (fr & 7)) * 8;
    int sLo = ((4 + sg) ^ (fr & 7)) * 8;

    s16x8 a0h,a0l,a1h,a1l,a2h,a2l,a3h,a3l;
    s16x8 p0h,p0l,p1h,p1l,q0h,q0l,q1h,q1l;

    // prologue: tile0 all 4 halves; tile1 A0+B0  (12 loads/wave)
    STAGE(0,0,0,0); STAGE(0,0,1,0); STAGE(0,1,0,0); STAGE(0,1,1,0);
    STAGE(1,0,0,1); STAGE(1,1,0,1);
    VMW4                                     // tile0 fully landed
    __builtin_amdgcn_s_barrier();

    for (int u = 0; u < 30; u += 2) {
        TILE(0, STAGE(1,1,1,u+1), STAGE(1,0,1,u+1),
                STAGE(0,0,0,u+2), STAGE(0,1,0,u+2), VMW4)
        TILE(1, STAGE(0,1,1,u+2), STAGE(0,0,1,u+2),
                STAGE(1,0,0,u+3), STAGE(1,1,0,u+3), VMW4)
    }
    // epilogue: tile 30 (stage 31.B1/31.A1, drain), tile 31 (pure compute)
    TILE(0, STAGE(1,1,1,31), STAGE(1,0,1,31), NOPS, NOPS, VMW0)
    TILE(1, NOPS, NOPS, NOPS, NOPS, )
}

// ---------------------------------------------------------------------------
// P1: transpose + split w_a|query into w_split[2048][32][64]
// ---------------------------------------------------------------------------
__global__ __launch_bounds__(256) void wsplit_kernel(
    const float* __restrict__ wa, const float* __restrict__ qu,
    u16* __restrict__ w_split)
{
    int idx = blockIdx.x * 256 + threadIdx.x;   // 0..1M-1
    int h = idx >> 10, n = idx & 1023;
    float va = wa[idx];
    float vq = qu[idx];
    size_t col = (size_t)(h >> 5) * 64 + (h & 31);
    size_t oa = (size_t)n * 2048 + col;
    size_t oq = (size_t)(1024 + n) * 2048 + col;
    w_split[oa]      = bf16_trunc(va);
    w_split[oa + 32] = bf16_rne(va - bf16_hi_f(va));
    w_split[oq]      = bf16_trunc(vq);
    w_split[oq + 32] = bf16_rne(vq - bf16_hi_f(vq));
}

// ---------------------------------------------------------------------------
// P2: read x once -> xT[b][h][t] (bf16, K4 B)  +  x_split (split, K1 A)
// ---------------------------------------------------------------------------
__global__ __launch_bounds__(256) void xprep_kernel(
    const float* __restrict__ x, u16* __restrict__ xT,
    u16* __restrict__ x_split)
{
    __shared__ u16 tile[64][65];
    int b = blockIdx.z;
    int t0 = blockIdx.x * 64;
    int h0 = blockIdx.y * 64;
    const float* xb = x + (size_t)b * NSEQ * NHID;
    int tid = threadIdx.x;
    #pragma unroll
    for (int i = 0; i < 16; i++) {
        int e = i * 256 + tid;
        int tl = e >> 6, hl = e & 63;
        float v = xb[(size_t)(t0 + tl) * NHID + h0 + hl];
        tile[tl][hl] = bf16_rne(v);
        int k = h0 + hl;
        size_t o = (size_t)(b * NSEQ + t0 + tl) * 2048 + (size_t)(k >> 5) * 64 + (k & 31);
        x_split[o]      = bf16_trunc(v);
        x_split[o + 32] = bf16_rne(v - bf16_hi_f(v));
    }
    __syncthreads();
    u16* xTb = xT + (size_t)b * NHID * NSEQ;
    #pragma unroll
    for (int i = 0; i < 16; i++) {
        int e = i * 256 + tid;
        int hl = e >> 6, tl = e & 63;
        xTb[(size_t)(h0 + hl) * NSEQ + t0 + tl] = tile[tl][hl];
    }
}

// ---------------------------------------------------------------------------
// K1: key = tanh(x @ w_a), q = x @ query  (256x256 8-phase split-bf16)
//     outputs written in split-interleaved layout for K2
// ---------------------------------------------------------------------------
__global__ __launch_bounds__(512, 2) void k1_gemm(
    const u16* __restrict__ x_split, const u16* __restrict__ w_split,
    u16* __restrict__ k_split, u16* __restrict__ q_split)
{
    extern __shared__ u16 lds[];
    int wg = blockIdx.x;                       // 1024 blocks
    int nid = (wg & 7) * 128 + (wg >> 3);      // XCD-chunked
    int n0 = (nid & 7) * 256;
    int m0 = (nid >> 3) * 256;
    bool is_key = (n0 < 1024);

    f32x4 acc[2][2][4][2] = {};
    gemm_core(x_split, m0, w_split, n0, lds, acc);

    int tid = threadIdx.x;
    int l = tid & 63, w = tid >> 6;
    int wr = w >> 2, wc = w & 3;
    int fr = l & 15, fq = l >> 4;
    u16* outp = is_key ? k_split : q_split;
    int nb = is_key ? n0 : (n0 - 1024);
    #pragma unroll
    for (int mh = 0; mh < 2; mh++)
    #pragma unroll
    for (int nh = 0; nh < 2; nh++)
    #pragma unroll
    for (int m = 0; m < 4; m++)
    #pragma unroll
    for (int n = 0; n < 2; n++)
    #pragma unroll
    for (int j = 0; j < 4; j++) {
        int grow = m0 + mh * 128 + wr * 64 + m * 16 + fq * 4 + j;
        int c    = nb + nh * 128 + wc * 32 + n * 16 + fr;
        float v = acc[mh][nh][m][n][j];
        if (is_key) v = fast_tanh(v);
        size_t o = (size_t)grow * 2048 + (size_t)(c >> 5) * 64 + (c & 31);
        outp[o]      = bf16_trunc(v);
        outp[o + 32] = bf16_rne(v - bf16_hi_f(v));
    }
}

// ---------------------------------------------------------------------------
// K2: logits[b][s][t] = q[b,s,:] . key[b,t,:]  (256x256 causal tiles only)
// ---------------------------------------------------------------------------
__global__ __launch_bounds__(512, 2) void k2_logits(
    const u16* __restrict__ q_split, const u16* __restrict__ k_split,
    float* __restrict__ dmat)
{
    extern __shared__ u16 lds[];
    int wg = blockIdx.x;                       // 576 blocks = 16 b * 36 tiles
    int nid = (wg & 7) * 72 + (wg >> 3);
    int b = nid / 36;
    int lin = nid - b * 36;
    int st = 0;
    while ((st + 1) * (st + 2) / 2 <= lin) st++;
    int tt = lin - st * (st + 1) / 2;
    int s0 = st * 256, t0 = tt * 256;
    int base = b * NSEQ;

    f32x4 acc[2][2][4][2] = {};
    gemm_core(q_split, base + s0, k_split, base + t0, lds, acc);

    float* db = dmat + (size_t)b * NSEQ * NSEQ;
    int tid = threadIdx.x;
    int l = tid & 63, w = tid >> 6;
    int wr = w >> 2, wc = w & 3;
    int fr = l & 15, fq = l >> 4;
    #pragma unroll
    for (int mh = 0; mh < 2; mh++)
    #pragma unroll
    for (int nh = 0; nh < 2; nh++)
    #pragma unroll
    for (int m = 0; m < 4; m++)
    #pragma unroll
    for (int n = 0; n < 2; n++)
    #pragma unroll
    for (int j = 0; j < 4; j++) {
        int s = s0 + mh * 128 + wr * 64 + m * 16 + fq * 4 + j;
        int t = t0 + nh * 128 + wc * 32 + n * 16 + fr;
        if (t <= s) db[(size_t)s * NSEQ + t] = acc[mh][nh][m][n][j];
    }
}

// ---------------------------------------------------------------------------
// K3: row-wise causal softmax, in place; also emit bf16 copy for K4.
// ---------------------------------------------------------------------------
__global__ __launch_bounds__(256) void k3_softmax(
    float* __restrict__ dmat, u16* __restrict__ d_bf16)
{
    __shared__ float redm[4];
    __shared__ float reds[4];
    int rowid = blockIdx.x;             // b*2048 + s
    int s = rowid & (NSEQ - 1);
    float* row = dmat + (size_t)rowid * NSEQ;
    int tid = threadIdx.x;
    int lane = tid & 63, w = tid >> 6;
    int t0 = tid * 8;

    float v[8];
    if (t0 <= s) {
        float4 a = *(const float4*)&row[t0];
        float4 c = *(const float4*)&row[t0 + 4];
        v[0] = a.x; v[1] = a.y; v[2] = a.z; v[3] = a.w;
        v[4] = c.x; v[5] = c.y; v[6] = c.z; v[7] = c.w;
        #pragma unroll
        for (int i = 0; i < 8; i++) if (t0 + i > s) v[i] = -INFINITY;
    } else {
        #pragma unroll
        for (int i = 0; i < 8; i++) v[i] = -INFINITY;
    }

    float m = -INFINITY;
    #pragma unroll
    for (int i = 0; i < 8; i++) m = fmaxf(m, v[i]);
    #pragma unroll
    for (int off = 32; off > 0; off >>= 1) m = fmaxf(m, __shfl_xor(m, off));
    if (lane == 0) redm[w] = m;
    __syncthreads();
    m = fmaxf(fmaxf(redm[0], redm[1]), fmaxf(redm[2], redm[3]));

    float sum = 0.f;
    float ev[8];
    #pragma unroll
    for (int i = 0; i < 8; i++) {
        ev[i] = (t0 + i <= s) ? __expf(v[i] - m) : 0.f;
        sum += ev[i];
    }
    #pragma unroll
    for (int off = 32; off > 0; off >>= 1) sum += __shfl_xor(sum, off);
    if (lane == 0) reds[w] = sum;
    __syncthreads();
    sum = reds[0] + reds[1] + reds[2] + reds[3];
    float inv = 1.0f / sum;

    float4 o0, o1;
    o0.x = ev[0] * inv; o0.y = ev[1] * inv; o0.z = ev[2] * inv; o0.w = ev[3] * inv;
    o1.x = ev[4] * inv; o1.y = ev[5] * inv; o1.z = ev[6] * inv; o1.w = ev[7] * inv;
    *(float4*)&row[t0] = o0;
    *(float4*)&row[t0 + 4] = o1;
    u16x8 bv;
    bv[0] = bf16_rne(o0.x); bv[1] = bf16_rne(o0.y); bv[2] = bf16_rne(o0.z); bv[3] = bf16_rne(o0.w);
    bv[4] = bf16_rne(o1.x); bv[5] = bf16_rne(o1.y); bv[6] = bf16_rne(o1.z); bv[7] = bf16_rne(o1.w);
    *(u16x8*)&d_bf16[(size_t)rowid * NSEQ + t0] = bv;
}

// ---------------------------------------------------------------------------
// K4: a = d @ x  (bf16 MFMA, gload_lds staging, K truncated at diagonal)
// ---------------------------------------------------------------------------
__global__ __launch_bounds__(256) void k4_av(
    const u16* __restrict__ d_bf16,
    const u16* __restrict__ xT,
    float* __restrict__ aout)
{
    __shared__ u16 sa[128 * 32];
    __shared__ u16 sb[128 * 32];

    int wg = blockIdx.x;
    int nid = (wg & 7) * 256 + (wg >> 3);
    int n0 = (nid & 7) * 128;
    int s0 = ((nid >> 3) & 15) * 128;
    int b = nid >> 7;

    int tid = threadIdx.x;
    int lane = tid & 63;
    int w = tid >> 6;
    int wr = w >> 1, wc = w & 1;

    int srow = w * 16 + (lane >> 2);
    int sslot = ((lane & 3) ^ ((lane >> 3) & 3)) * 8;

    const u16* pa = d_bf16 + (size_t)(b * NSEQ + s0 + srow) * NSEQ + sslot;
    const u16* pb = xT + ((size_t)b * NHID + n0 + srow) * NSEQ + sslot;
    u16* da0 = &sa[(w * 16) * 32];  u16* da1 = &sa[(64 + w * 16) * 32];
    u16* db0 = &sb[(w * 16) * 32];  u16* db1 = &sb[(64 + w * 16) * 32];
    const size_t R64 = (size_t)64 * NSEQ;

    int fr = lane & 15, sg = lane >> 4;
    int rsl = (sg ^ ((fr >> 1) & 3)) * 8;

    f32x4 acc[4][4] = {};
    int kmax = s0 + 128;            // d[s][t] == 0 for t > s

    for (int kk = 0; kk < kmax; kk += 32) {
        __syncthreads();
        GLOAD16(pa + kk, da0); GLOAD16(pa + kk + R64, da1);
        GLOAD16(pb + kk, db0); GLOAD16(pb + kk + R64, db1);
        __syncthreads();

        s16x8 af[4], bf[4];
        #pragma unroll
        for (int m = 0; m < 4; m++)
            af[m] = *(const s16x8*)&sa[(wr * 64 + m * 16 + fr) * 32 + rsl];
        #pragma unroll
        for (int n = 0; n < 4; n++)
            bf[n] = *(const s16x8*)&sb[(wc * 64 + n * 16 + fr) * 32 + rsl];
        #pragma unroll
        for (int m = 0; m < 4; m++)
            #pragma unroll
            for (int n = 0; n < 4; n++)
                acc[m][n] = __builtin_amdgcn_mfma_f32_16x16x32_bf16(af[m], bf[n], acc[m][n], 0, 0, 0);
    }

    float* ab = aout + (size_t)b * NSEQ * NHID;
    int fq = lane >> 4;
    #pragma unroll
    for (int m = 0; m < 4; m++)
        #pragma unroll
        for (int n = 0; n < 4; n++)
            #pragma unroll
            for (int j = 0; j < 4; j++) {
                int s = s0 + wr * 64 + m * 16 + fq * 4 + j;
                int h = n0 + wc * 64 + n * 16 + fr;
                ab[(size_t)s * NHID + h] = acc[m][n][j];
            }
}

// ---------------------------------------------------------------------------
extern "C" void kernel_launch(void* const* d_in, const int* in_sizes, int n_in,
                              void* d_out, int out_size, void* d_ws, size_t ws_size,
                              hipStream_t stream)
{
    const float* x     = (const float*)d_in[0];
    const float* w_a   = (const float*)d_in[1];
    const float* query = (const float*)d_in[2];

    float* aout = (float*)d_out;                         // [16][2048][1024]
    float* dmat = aout + (size_t)NBATCH * NSEQ * NHID;   // [16][2048][2048]

    const size_t NSPL = (size_t)MALL * 2048;             // 67,108,864 u16 (128MB)
    char* p = (char*)d_ws;
    u16* q_split = (u16*)p; p += NSPL * 2;
    u16* k_split = (u16*)p; p += NSPL * 2;
    u16* x_split = (u16*)p; p += NSPL * 2;               // dead after K1
    u16* d_bf16  = x_split;                              // alias (exact size match)
    u16* xT      = (u16*)p; p += (size_t)MALL * 1024 * 2;
    u16* w_split = (u16*)p; p += (size_t)2048 * 2048 * 2;
    (void)ws_size; (void)in_sizes; (void)n_in; (void)out_size;

    hipFuncSetAttribute((const void*)k1_gemm,
                        hipFuncAttributeMaxDynamicSharedMemorySize, 131072);
    hipFuncSetAttribute((const void*)k2_logits,
                        hipFuncAttributeMaxDynamicSharedMemorySize, 131072);

    wsplit_kernel<<<dim3(4096), 256, 0, stream>>>(w_a, query, w_split);
    xprep_kernel<<<dim3(32, 16, 16), 256, 0, stream>>>(x, xT, x_split);
    k1_gemm<<<dim3(1024), 512, 131072, stream>>>(x_split, w_split, k_split, q_split);
    k2_logits<<<dim3(576), 512, 131072, stream>>>(q_split, k_split, dmat);
    k3_softmax<<<dim3(32768), 256, 0, stream>>>(dmat, d_bf16);
    k4_av<<<dim3(2048), 256, 0, stream>>>(d_bf16, xT, aout);
}

// Round 5
// 653.377 us; speedup vs baseline: 1.8250x; 1.3779x over previous
//
#include <hip/hip_runtime.h>

typedef _Float16 f16x8 __attribute__((ext_vector_type(8)));
typedef float f32x4 __attribute__((ext_vector_type(4)));
typedef unsigned short u16;
typedef u16 u16x8 __attribute__((ext_vector_type(8)));

#define NBATCH 16
#define NSEQ   2048
#define NHID   1024
#define MALL   (NBATCH * NSEQ)   // 32768

__device__ __forceinline__ u16 f16_rne(float x) {
    _Float16 h = (_Float16)x;
    return __builtin_bit_cast(u16, h);
}
__device__ __forceinline__ float fast_tanh(float x) {
    float e = __expf(2.0f * x);
    return 1.0f - 2.0f / (e + 1.0f);
}

#define GLOAD16(g, l) __builtin_amdgcn_global_load_lds(                         \
    (const __attribute__((address_space(1))) unsigned int*)(g),                 \
    (__attribute__((address_space(3))) unsigned int*)(l), 16, 0, 0)

// ===========================================================================
// 256x256 2-phase-per-K-tile f16 GEMM core.
// TERMS=2: B split layout [rows][32 kt][64] u16 (cols 0-31 f16-hi, 32-63
//          f16-lo of 64*w); MM = ah*bh + ah*bl.  A plain [rows][1024] f16.
// TERMS=1: both plain [rows][1024] f16; MM = ah*bh.
// LDS/buffer: A 256x32 u16 (16KB) + B 256x(64|32) u16 (32|16KB); x2 buffers.
// Swizzles (involution, applied at global source and on ds_read):
//   64-wide: slot' = slot ^ (row&7);  32-wide: slot' = slot ^ ((row>>1)&3)
// Per K-tile: 2 phases; phase A computes nh=0 (16 slots), phase B nh=1.
// Stagger: phase A stages OTHER buf (t+1 H1); phase B stages OWN buf (t+2 H0)
// — own-buffer halves are only written after their phase-A reads retired.
// vmcnt: never 0 in main loop; steady N = loads-per-stage-group (3 / 2).
// ===========================================================================

#define NOPS ((void)0)

#define MMBLK(NH, J0, J1)                                                      \
    MM(acc[0][NH][0][0],0,J0); MM(acc[0][NH][0][1],0,J1);                      \
    MM(acc[0][NH][1][0],1,J0); MM(acc[0][NH][1][1],1,J1);                      \
    MM(acc[0][NH][2][0],2,J0); MM(acc[0][NH][2][1],2,J1);                      \
    MM(acc[0][NH][3][0],3,J0); MM(acc[0][NH][3][1],3,J1);                      \
    MM(acc[1][NH][0][0],4,J0); MM(acc[1][NH][0][1],4,J1);                      \
    MM(acc[1][NH][1][0],5,J0); MM(acc[1][NH][1][1],5,J1);                      \
    MM(acc[1][NH][2][0],6,J0); MM(acc[1][NH][2][1],6,J1);                      \
    MM(acc[1][NH][3][0],7,J0); MM(acc[1][NH][3][1],7,J1);

#define TILE2(C, ST0, ST1, W) {                                                \
    LDA(0,C,0); LDA(1,C,0); LDA(2,C,0); LDA(3,C,0);                            \
    LDA(4,C,1); LDA(5,C,1); LDA(6,C,1); LDA(7,C,1);                            \
    LDB(0,C,0); LDB(1,C,0);                                                    \
    ST0;                                                                       \
    __builtin_amdgcn_s_barrier();                                              \
    asm volatile("s_waitcnt lgkmcnt(0)" ::: "memory");                         \
    __builtin_amdgcn_sched_barrier(0);                                         \
    __builtin_amdgcn_s_setprio(1);                                             \
    MMBLK(0, 0, 1)                                                             \
    __builtin_amdgcn_s_setprio(0);                                             \
    __builtin_amdgcn_s_barrier();                                              \
    LDB(2,C,1); LDB(3,C,1);                                                    \
    ST1;                                                                       \
    __builtin_amdgcn_s_barrier();                                              \
    asm volatile("s_waitcnt lgkmcnt(0)" ::: "memory");                         \
    __builtin_amdgcn_sched_barrier(0);                                         \
    __builtin_amdgcn_s_setprio(1);                                             \
    MMBLK(1, 2, 3)                                                             \
    __builtin_amdgcn_s_setprio(0);                                             \
    W;                                                                         \
    __builtin_amdgcn_s_barrier();                                              \
}

template<int TERMS>
__device__ __forceinline__ void gemm_core(
    const u16* __restrict__ Ap, int Arow0,
    const u16* __restrict__ Bp, int Brow0,
    u16* lds, f32x4 (&acc)[2][2][4][2])
{
    constexpr int BW   = (TERMS == 2) ? 64 : 32;
    constexpr int ASZ  = 256 * 32;
    constexpr int BUFS = ASZ + 256 * BW;

    int tid = threadIdx.x;
    int l = tid & 63, w = tid >> 6;            // lane, wave 0..7
    int wr = w >> 2, wc = w & 3;               // 2M x 4N wave grid
    int fr = l & 15, sg = l >> 4;
    int sHi = (sg ^ (fr & 7)) * 8;             // 64-wide slots
    int sLo = ((4 + sg) ^ (fr & 7)) * 8;
    int rsl = (sg ^ ((fr >> 1) & 3)) * 8;      // 32-wide slots

    f16x8 ah[8], bh[4], bl[4];

    auto LDA = [&](int i, int C, int MH) {
        int rb = MH * 128 + wr * 64 + (i & 3) * 16 + fr;
        ah[i] = *(const f16x8*)&lds[C * BUFS + rb * 32 + rsl];
    };
    auto LDB = [&](int j, int C, int NH) {
        int rb = NH * 128 + wc * 32 + (j & 1) * 16 + fr;
        if constexpr (TERMS == 2) {
            bh[j] = *(const f16x8*)&lds[C * BUFS + ASZ + rb * 64 + sHi];
            bl[j] = *(const f16x8*)&lds[C * BUFS + ASZ + rb * 64 + sLo];
        } else {
            bh[j] = *(const f16x8*)&lds[C * BUFS + ASZ + rb * 32 + rsl];
        }
    };
    auto MM = [&](f32x4& d, int i, int j) {
        d = __builtin_amdgcn_mfma_f32_16x16x32_f16(ah[i], bh[j], d, 0, 0, 0);
        if constexpr (TERMS == 2)
            d = __builtin_amdgcn_mfma_f32_16x16x32_f16(ah[i], bl[j], d, 0, 0, 0);
    };
    auto STA = [&](int C, int H, int T) {
        int rg = Arow0 + H * 128 + w * 16 + (l >> 2);
        const u16* s = Ap + (size_t)rg * 1024 + (size_t)T * 32
                       + ((l & 3) ^ ((rg >> 1) & 3)) * 8;
        u16* d = &lds[C * BUFS + (H * 128 + w * 16) * 32];
        GLOAD16(s, d);
    };
    auto STB = [&](int C, int H, int T) {
        if constexpr (TERMS == 2) {
            int rg = Brow0 + H * 128 + w * 8 + (l >> 3);
            const u16* s = Bp + (size_t)rg * 2048 + (size_t)T * 64
                           + ((l & 7) ^ (rg & 7)) * 8;
            u16* d = &lds[C * BUFS + ASZ + (H * 128 + w * 8) * 64];
            GLOAD16(s, d);
            GLOAD16(s + (size_t)64 * 2048, d + 64 * 64);
        } else {
            int rg = Brow0 + H * 128 + w * 16 + (l >> 2);
            const u16* s = Bp + (size_t)rg * 1024 + (size_t)T * 32
                           + ((l & 3) ^ ((rg >> 1) & 3)) * 8;
            u16* d = &lds[C * BUFS + ASZ + (H * 128 + w * 16) * 32];
            GLOAD16(s, d);
        }
    };
    auto WS = [&]() {
        if constexpr (TERMS == 2) asm volatile("s_waitcnt vmcnt(3)" ::: "memory");
        else                      asm volatile("s_waitcnt vmcnt(2)" ::: "memory");
    };

    // prologue: tile0 fully; tile1 first halves
    STA(0, 0, 0); STA(0, 1, 0); STB(0, 0, 0); STB(0, 1, 0);
    STA(1, 0, 1); STB(1, 0, 1);
    WS();
    __builtin_amdgcn_s_barrier();

    for (int u = 0; u < 30; u += 2) {
        TILE2(0, (STA(1,1,u+1), STB(1,1,u+1)), (STA(0,0,u+2), STB(0,0,u+2)), WS())
        TILE2(1, (STA(0,1,u+2), STB(0,1,u+2)), (STA(1,0,u+3), STB(1,0,u+3)), WS())
    }
    TILE2(0, (STA(1,1,31), STB(1,1,31)), NOPS,
          asm volatile("s_waitcnt vmcnt(0)" ::: "memory"))
    TILE2(1, NOPS, NOPS, NOPS)
}

// ---------------------------------------------------------------------------
// P1: w_split[2048][32][64]: f16 2-level split of 64*w (rows 0-1023 = w_a,
//     1024-2047 = query), transposed to [n][k] order.
// ---------------------------------------------------------------------------
__global__ __launch_bounds__(256) void wsplit_kernel(
    const float* __restrict__ wa, const float* __restrict__ qu,
    u16* __restrict__ w_split)
{
    int idx = blockIdx.x * 256 + threadIdx.x;   // 0..1M-1
    int h = idx >> 10, n = idx & 1023;
    float va = wa[idx] * 64.0f;
    float vq = qu[idx] * 64.0f;
    size_t col = (size_t)(h >> 5) * 64 + (h & 31);
    size_t oa = (size_t)n * 2048 + col;
    size_t oq = (size_t)(1024 + n) * 2048 + col;
    _Float16 ha = (_Float16)va;
    _Float16 la = (_Float16)(va - (float)ha);
    _Float16 hq = (_Float16)vq;
    _Float16 lq = (_Float16)(vq - (float)hq);
    w_split[oa]      = __builtin_bit_cast(u16, ha);
    w_split[oa + 32] = __builtin_bit_cast(u16, la);
    w_split[oq]      = __builtin_bit_cast(u16, hq);
    w_split[oq + 32] = __builtin_bit_cast(u16, lq);
}

// ---------------------------------------------------------------------------
// P2: read x once -> x_f16 [b*2048+t][1024] (K1 A) + xT_f16 [b][h][t] (K4 B)
// ---------------------------------------------------------------------------
__global__ __launch_bounds__(256) void xprep_kernel(
    const float* __restrict__ x, u16* __restrict__ xT,
    u16* __restrict__ x_f16)
{
    __shared__ u16 tile[64][65];
    int b = blockIdx.z;
    int t0 = blockIdx.x * 64;
    int h0 = blockIdx.y * 64;
    const float* xb = x + (size_t)b * NSEQ * NHID;
    int tid = threadIdx.x;
    #pragma unroll
    for (int i = 0; i < 16; i++) {
        int e = i * 256 + tid;
        int tl = e >> 6, hl = e & 63;
        float v = xb[(size_t)(t0 + tl) * NHID + h0 + hl];
        u16 bv = f16_rne(v);
        tile[tl][hl] = bv;
        x_f16[(size_t)(b * NSEQ + t0 + tl) * NHID + h0 + hl] = bv;
    }
    __syncthreads();
    u16* xTb = xT + (size_t)b * NHID * NSEQ;
    #pragma unroll
    for (int i = 0; i < 16; i++) {
        int e = i * 256 + tid;
        int hl = e >> 6, tl = e & 63;
        xTb[(size_t)(h0 + hl) * NSEQ + t0 + tl] = tile[tl][hl];
    }
}

// ---------------------------------------------------------------------------
// K1: key = tanh(x @ w_a), q = x @ query   (f16 2-term, B scaled by 64)
// ---------------------------------------------------------------------------
__global__ __launch_bounds__(512, 2) void k1_gemm(
    const u16* __restrict__ x_f16, const u16* __restrict__ w_split,
    u16* __restrict__ k_f16, u16* __restrict__ q_f16)
{
    extern __shared__ u16 lds[];
    int wg = blockIdx.x;                       // 1024 blocks
    int nid = (wg & 7) * 128 + (wg >> 3);      // XCD-chunked
    int n0 = (nid & 7) * 256;
    int m0 = (nid >> 3) * 256;
    bool is_key = (n0 < 1024);

    f32x4 acc[2][2][4][2] = {};
    gemm_core<2>(x_f16, m0, w_split, n0, lds, acc);

    int tid = threadIdx.x;
    int l = tid & 63, w = tid >> 6;
    int wr = w >> 2, wc = w & 3;
    int fr = l & 15, fq = l >> 4;
    int nb = is_key ? n0 : (n0 - 1024);
    u16* outp = is_key ? k_f16 : q_f16;
    #pragma unroll
    for (int mh = 0; mh < 2; mh++)
    #pragma unroll
    for (int nh = 0; nh < 2; nh++)
    #pragma unroll
    for (int m = 0; m < 4; m++)
    #pragma unroll
    for (int n = 0; n < 2; n++)
    #pragma unroll
    for (int j = 0; j < 4; j++) {
        int grow = m0 + mh * 128 + wr * 64 + m * 16 + fq * 4 + j;
        int c    = nb + nh * 128 + wc * 32 + n * 16 + fr;
        float v = acc[mh][nh][m][n][j] * 0.015625f;   // /64 (B was scaled)
        outp[(size_t)grow * 1024 + c] = f16_rne(is_key ? fast_tanh(v) : v);
    }
}

// ---------------------------------------------------------------------------
// K2: logits = q . key  (causal 256x256 tiles, f16 1-term)
// ---------------------------------------------------------------------------
__global__ __launch_bounds__(512, 2) void k2_logits(
    const u16* __restrict__ q_f16, const u16* __restrict__ k_f16,
    float* __restrict__ dmat)
{
    extern __shared__ u16 lds[];
    int wg = blockIdx.x;                       // 576 = 16 b * 36 tiles
    int nid = (wg & 7) * 72 + (wg >> 3);
    int b = nid / 36;
    int lin = nid - b * 36;
    int st = 0;
    while ((st + 1) * (st + 2) / 2 <= lin) st++;
    int tt = lin - st * (st + 1) / 2;
    int s0 = st * 256, t0 = tt * 256;
    int base = b * NSEQ;

    f32x4 acc[2][2][4][2] = {};
    gemm_core<1>(q_f16, base + s0, k_f16, base + t0, lds, acc);

    float* db = dmat + (size_t)b * NSEQ * NSEQ;
    int tid = threadIdx.x;
    int l = tid & 63, w = tid >> 6;
    int wr = w >> 2, wc = w & 3;
    int fr = l & 15, fq = l >> 4;
    #pragma unroll
    for (int mh = 0; mh < 2; mh++)
    #pragma unroll
    for (int nh = 0; nh < 2; nh++)
    #pragma unroll
    for (int m = 0; m < 4; m++)
    #pragma unroll
    for (int n = 0; n < 2; n++)
    #pragma unroll
    for (int j = 0; j < 4; j++) {
        int s = s0 + mh * 128 + wr * 64 + m * 16 + fq * 4 + j;
        int t = t0 + nh * 128 + wc * 32 + n * 16 + fr;
        if (t <= s) db[(size_t)s * NSEQ + t] = acc[mh][nh][m][n][j];
    }
}

// ---------------------------------------------------------------------------
// K3: row-wise causal softmax, in place; also emit f16 copy for K4.
// ---------------------------------------------------------------------------
__global__ __launch_bounds__(256) void k3_softmax(
    float* __restrict__ dmat, u16* __restrict__ d_f16)
{
    __shared__ float redm[4];
    __shared__ float reds[4];
    int rowid = blockIdx.x;             // b*2048 + s
    int s = rowid & (NSEQ - 1);
    float* row = dmat + (size_t)rowid * NSEQ;
    int tid = threadIdx.x;
    int lane = tid & 63, w = tid >> 6;
    int t0 = tid * 8;

    float v[8];
    if (t0 <= s) {
        float4 a = *(const float4*)&row[t0];
        float4 c = *(const float4*)&row[t0 + 4];
        v[0] = a.x; v[1] = a.y; v[2] = a.z; v[3] = a.w;
        v[4] = c.x; v[5] = c.y; v[6] = c.z; v[7] = c.w;
        #pragma unroll
        for (int i = 0; i < 8; i++) if (t0 + i > s) v[i] = -INFINITY;
    } else {
        #pragma unroll
        for (int i = 0; i < 8; i++) v[i] = -INFINITY;
    }

    float m = -INFINITY;
    #pragma unroll
    for (int i = 0; i < 8; i++) m = fmaxf(m, v[i]);
    #pragma unroll
    for (int off = 32; off > 0; off >>= 1) m = fmaxf(m, __shfl_xor(m, off));
    if (lane == 0) redm[w] = m;
    __syncthreads();
    m = fmaxf(fmaxf(redm[0], redm[1]), fmaxf(redm[2], redm[3]));

    float sum = 0.f;
    float ev[8];
    #pragma unroll
    for (int i = 0; i < 8; i++) {
        ev[i] = (t0 + i <= s) ? __expf(v[i] - m) : 0.f;
        sum += ev[i];
    }
    #pragma unroll
    for (int off = 32; off > 0; off >>= 1) sum += __shfl_xor(sum, off);
    if (lane == 0) reds[w] = sum;
    __syncthreads();
    sum = reds[0] + reds[1] + reds[2] + reds[3];
    float inv = 1.0f / sum;

    float4 o0, o1;
    o0.x = ev[0] * inv; o0.y = ev[1] * inv; o0.z = ev[2] * inv; o0.w = ev[3] * inv;
    o1.x = ev[4] * inv; o1.y = ev[5] * inv; o1.z = ev[6] * inv; o1.w = ev[7] * inv;
    *(float4*)&row[t0] = o0;
    *(float4*)&row[t0 + 4] = o1;
    u16x8 bv;
    bv[0] = f16_rne(o0.x); bv[1] = f16_rne(o0.y); bv[2] = f16_rne(o0.z); bv[3] = f16_rne(o0.w);
    bv[4] = f16_rne(o1.x); bv[5] = f16_rne(o1.y); bv[6] = f16_rne(o1.z); bv[7] = f16_rne(o1.w);
    *(u16x8*)&d_f16[(size_t)rowid * NSEQ + t0] = bv;
}

// ---------------------------------------------------------------------------
// K4: a = d @ x  (f16 MFMA, gload_lds staging, K truncated at diagonal)
// ---------------------------------------------------------------------------
__global__ __launch_bounds__(256) void k4_av(
    const u16* __restrict__ d_f16,
    const u16* __restrict__ xT,
    float* __restrict__ aout)
{
    __shared__ u16 sa[128 * 32];
    __shared__ u16 sb[128 * 32];

    int wg = blockIdx.x;
    int nid = (wg & 7) * 256 + (wg >> 3);
    int n0 = (nid & 7) * 128;
    int s0 = ((nid >> 3) & 15) * 128;
    int b = nid >> 7;

    int tid = threadIdx.x;
    int lane = tid & 63;
    int w = tid >> 6;
    int wr = w >> 1, wc = w & 1;

    int srow = w * 16 + (lane >> 2);
    int sslot = ((lane & 3) ^ ((lane >> 3) & 3)) * 8;

    const u16* pa = d_f16 + (size_t)(b * NSEQ + s0 + srow) * NSEQ + sslot;
    const u16* pb = xT + ((size_t)b * NHID + n0 + srow) * NSEQ + sslot;
    u16* da0 = &sa[(w * 16) * 32];  u16* da1 = &sa[(64 + w * 16) * 32];
    u16* db0 = &sb[(w * 16) * 32];  u16* db1 = &sb[(64 + w * 16) * 32];
    const size_t R64 = (size_t)64 * NSEQ;

    int fr = lane & 15, sg = lane >> 4;
    int rsl = (sg ^ ((fr >> 1) & 3)) * 8;

    f32x4 acc[4][4] = {};
    int kmax = s0 + 128;            // d[s][t] == 0 for t > s

    for (int kk = 0; kk < kmax; kk += 32) {
        __syncthreads();
        GLOAD16(pa + kk, da0); GLOAD16(pa + kk + R64, da1);
        GLOAD16(pb + kk, db0); GLOAD16(pb + kk + R64, db1);
        __syncthreads();

        f16x8 af[4], bf[4];
        #pragma unroll
        for (int m = 0; m < 4; m++)
            af[m] = *(const f16x8*)&sa[(wr * 64 + m * 16 + fr) * 32 + rsl];
        #pragma unroll
        for (int n = 0; n < 4; n++)
            bf[n] = *(const f16x8*)&sb[(wc * 64 + n * 16 + fr) * 32 + rsl];
        #pragma unroll
        for (int m = 0; m < 4; m++)
            #pragma unroll
            for (int n = 0; n < 4; n++)
                acc[m][n] = __builtin_amdgcn_mfma_f32_16x16x32_f16(af[m], bf[n], acc[m][n], 0, 0, 0);
    }

    float* ab = aout + (size_t)b * NSEQ * NHID;
    int fq = lane >> 4;
    #pragma unroll
    for (int m = 0; m < 4; m++)
        #pragma unroll
        for (int n = 0; n < 4; n++)
            #pragma unroll
            for (int j = 0; j < 4; j++) {
                int s = s0 + wr * 64 + m * 16 + fq * 4 + j;
                int h = n0 + wc * 64 + n * 16 + fr;
                ab[(size_t)s * NHID + h] = acc[m][n][j];
            }
}

// ---------------------------------------------------------------------------
extern "C" void kernel_launch(void* const* d_in, const int* in_sizes, int n_in,
                              void* d_out, int out_size, void* d_ws, size_t ws_size,
                              hipStream_t stream)
{
    const float* x     = (const float*)d_in[0];
    const float* w_a   = (const float*)d_in[1];
    const float* query = (const float*)d_in[2];

    float* aout = (float*)d_out;                         // [16][2048][1024]
    float* dmat = aout + (size_t)NBATCH * NSEQ * NHID;   // [16][2048][2048]

    char* p = (char*)d_ws;
    u16* q_f16  = (u16*)p; p += (size_t)MALL * 1024 * 2;    // 64MB
    u16* x_f16  = (u16*)p; p += (size_t)MALL * 1024 * 2;    // 64MB (dead after K1)
    u16* k_f16  = (u16*)p; p += (size_t)MALL * 1024 * 2;    // 64MB (dead after K2)
    u16* d_f16  = x_f16;                                    // alias x_f16+k_f16 (128MB)
    u16* xT     = (u16*)p; p += (size_t)MALL * 1024 * 2;    // 64MB
    u16* w_split = (u16*)p; p += (size_t)2048 * 2048 * 2;   // 8MB
    (void)ws_size; (void)in_sizes; (void)n_in; (void)out_size;

    hipFuncSetAttribute((const void*)k1_gemm,
                        hipFuncAttributeMaxDynamicSharedMemorySize, 98304);
    hipFuncSetAttribute((const void*)k2_logits,
                        hipFuncAttributeMaxDynamicSharedMemorySize, 65536);

    wsplit_kernel<<<dim3(4096), 256, 0, stream>>>(w_a, query, w_split);
    xprep_kernel<<<dim3(32, 16, 16), 256, 0, stream>>>(x, xT, x_f16);
    k1_gemm<<<dim3(1024), 512, 98304, stream>>>(x_f16, w_split, k_f16, q_f16);
    k2_logits<<<dim3(576), 512, 65536, stream>>>(q_f16, k_f16, dmat);
    k3_softmax<<<dim3(32768), 256, 0, stream>>>(dmat, d_f16);
    k4_av<<<dim3(2048), 256, 0, stream>>>(d_f16, xT, aout);
}